// Round 11
// baseline (173.844 us; speedup 1.0000x reference)
//
#include <hip/hip_runtime.h>
#include <math.h>

#define HIDDEN 1024
#define NL 9
#define LEAN_TAU 0.25f
#define LEAN_DELTA 0.35f
#define LCH 16  // CRF scan chunk length
#define TPR 4   // tokens per 16-lane row per iteration (16 tokens/wave-iter)

// ---------------- Kernel 1: emission logits + lean adjust ----------------
// R11: wave = 4 rows x TPR tokens; lane c in [0,16) owns k-slice [c*16,c*16+16)
// of each 256-float phase. Weights in LDS with (q,c)-swizzled layout so the 16
// c-lanes hit all 32 banks (2-way, free); 4 r-lanes broadcast (free).
// Per token: 9 ds_read_b128 + 9 shfl (4-step butterfly inside rows, serves 4
// rows at once) ~ 160 cyc DS (vs R8's 750); 144 fma VALU; 4 VMEM.
// 12 waves/CU (VGPR~150, 3 blocks/CU), grid-stride over 768 blocks.
__global__ __launch_bounds__(256, 3) void logits_k(
    const float* __restrict__ hs, const float* __restrict__ w,
    const float* __restrict__ bias, const int* __restrict__ amask,
    float* __restrict__ e, int B, int T) {
  const int TOK = T - 2;
  const int nTok = B * TOK;
  __shared__ float lw[NL * HIDDEN];
  // stage weights swizzled: src k -> dst (k>>8)*256 + ((k>>2)&3)*64 + ((k>>4)&15)*4 + (k&3)
  for (int idx = threadIdx.x; idx < NL * HIDDEN; idx += 256) {
    const int l = idx >> 10, k = idx & 1023;
    const int dst =
        ((k >> 8) << 8) + (((k >> 2) & 3) << 6) + (((k >> 4) & 15) << 2) + (k & 3);
    lw[(l << 10) + dst] = w[idx];
  }
  __syncthreads();

  const int wave = threadIdx.x >> 6, lane = threadIdx.x & 63;
  const int r = lane >> 4, c = lane & 15;
  float bb[NL];
#pragma unroll
  for (int l = 0; l < NL; ++l) bb[l] = bias[l];

  const int nIter = nTok >> 4;  // 2040 (exact: 32640 = 16*2040)
  for (int it = blockIdx.x * 4 + wave; it < nIter; it += gridDim.x * 4) {
    const int base = it << 4;
    size_t off[TPR];
    int tb[TPR], tt[TPR];
#pragma unroll
    for (int tr = 0; tr < TPR; ++tr) {
      const int tok = base + r * TPR + tr;
      const int b = tok / TOK, t = tok - b * TOK;
      tb[tr] = b; tt[tr] = t;
      off[tr] = ((size_t)b * T + t + 1) * HIDDEN;
    }
    float acc[TPR][NL];
#pragma unroll
    for (int tr = 0; tr < TPR; ++tr)
#pragma unroll
      for (int l = 0; l < NL; ++l) acc[tr][l] = 0.f;

#pragma unroll
    for (int p = 0; p < 4; ++p) {  // K phases of 256
      float4 hv[TPR][4];
#pragma unroll
      for (int tr = 0; tr < TPR; ++tr)
#pragma unroll
        for (int q = 0; q < 4; ++q)
          hv[tr][q] = *reinterpret_cast<const float4*>(
              hs + off[tr] + p * 256 + c * 16 + q * 4);
#pragma unroll
      for (int l = 0; l < NL; ++l) {
        float4 wl[4];
#pragma unroll
        for (int q = 0; q < 4; ++q)
          wl[q] = *reinterpret_cast<const float4*>(
              &lw[(l << 10) + p * 256 + q * 64 + c * 4]);
#pragma unroll
        for (int tr = 0; tr < TPR; ++tr) {
          float a = acc[tr][l];
#pragma unroll
          for (int q = 0; q < 4; ++q)
            a = fmaf(hv[tr][q].x, wl[q].x,
                fmaf(hv[tr][q].y, wl[q].y,
                fmaf(hv[tr][q].z, wl[q].z, fmaf(hv[tr][q].w, wl[q].w, a))));
          acc[tr][l] = a;
        }
      }
    }

    // 4-step butterfly (xor 1,2,4,8 stays within each 16-lane row);
    // afterwards every lane of the row holds the token's full sums.
#pragma unroll
    for (int tr = 0; tr < TPR; ++tr)
#pragma unroll
      for (int l = 0; l < NL; ++l) {
        float v = acc[tr][l];
        v += __shfl_xor(v, 1);
        v += __shfl_xor(v, 2);
        v += __shfl_xor(v, 4);
        v += __shfl_xor(v, 8);
        acc[tr][l] = v + bb[l];
      }

#pragma unroll
    for (int tr = 0; tr < TPR; ++tr) {
      float m1 = -INFINITY, m2 = -INFINITY;
#pragma unroll
      for (int l = 0; l < NL; ++l) {
        const float v = acc[tr][l];
        if (v > m1) { m2 = m1; m1 = v; }
        else if (v > m2) { m2 = v; }
      }
      float vout = acc[tr][0];
#pragma unroll
      for (int l = 1; l < NL; ++l)
        if (c == l) vout = acc[tr][l];
      if (c == 0) {
        const bool unc = (m1 - m2 < LEAN_TAU) &&
                         (amask[tb[tr] * T + tt[tr] + 1] != 0);
        if (unc) vout += LEAN_DELTA;
      }
      const int tok = base + r * TPR + tr;
      if (c < NL) e[(size_t)tok * NL + c] = vout;
    }
  }
}

// ---------------- Kernel 2: per-chunk log-space matrix products ----------------
// 7 chunks per wave; lane = sub*9 + i holds row i of chunk sub's 9x9 product.
// Factored logsumexp: W = exp(trans) in registers -> 9 exp + 9 log + 81 fma/step.
__global__ __launch_bounds__(64) void chunk_k(
    const float* __restrict__ e, const int* __restrict__ labels,
    const float* __restrict__ trans, float* __restrict__ Pout,
    int B, int T, int C) {
  const int TOK = T - 2;
  __shared__ float e2[7][LCH][NL];
  __shared__ float tr2[NL * NL];
  __shared__ int msk[7][LCH];
  const int tid = threadIdx.x;
  const int nG = B * C;
  const int gbase = blockIdx.x * 7;

  for (int idx = tid; idx < NL * NL; idx += 64) tr2[idx] = trans[idx];
  for (int idx = tid; idx < 7 * LCH * NL; idx += 64) {
    const int sub = idx / (LCH * NL), rem = idx % (LCH * NL);
    const int step = rem / NL, j = rem % NL;
    const int g = gbase + sub;
    if (g < nG) {
      const int b = g / C, c = g % C;
      const int t = 1 + c * LCH + step;
      if (t < TOK) e2[sub][step][j] = e[((size_t)b * TOK + t) * NL + j];
    }
  }
  for (int idx = tid; idx < 7 * LCH; idx += 64) {
    const int sub = idx / LCH, step = idx % LCH;
    const int g = gbase + sub;
    if (g < nG) {
      const int b = g / C, c = g % C;
      const int t = 1 + c * LCH + step;
      msk[sub][step] = (t < TOK) ? (labels[(size_t)b * T + 1 + t] != -100) : 0;
    }
  }
  __syncthreads();

  const int sub = tid / NL, i = tid % NL;  // sub==7 only for tid 63 (inactive)
  const int g = gbase + sub;
  const bool act = (sub < 7) && (g < nG);
  int len = 1;
  if (act) { const int c = g % C; len = min(LCH, TOK - (1 + c * LCH)); }

  float W[NL][NL];
#pragma unroll
  for (int k = 0; k < NL; ++k)
#pragma unroll
    for (int j = 0; j < NL; ++j) W[k][j] = __expf(tr2[k * NL + j]);

  float P[NL];
  {
    const int m0 = act ? msk[sub][0] : 0;
#pragma unroll
    for (int j = 0; j < NL; ++j)
      P[j] = m0 ? (tr2[i * NL + j] + e2[sub][0][j])
                : ((i == j) ? 0.f : -1e30f);
  }
  for (int step = 1; step < len; ++step) {
    const int mt = msk[sub][step];
    float mx = P[0];
#pragma unroll
    for (int k = 1; k < NL; ++k) mx = fmaxf(mx, P[k]);
    float E[NL];
#pragma unroll
    for (int k = 0; k < NL; ++k) E[k] = __expf(P[k] - mx);
    float Pn[NL];
#pragma unroll
    for (int j = 0; j < NL; ++j) {
      float s = 0.f;
#pragma unroll
      for (int k = 0; k < NL; ++k) s = fmaf(E[k], W[k][j], s);
      Pn[j] = mx + __logf(s) + e2[sub][step][j];
    }
#pragma unroll
    for (int j = 0; j < NL; ++j) P[j] = mt ? Pn[j] : P[j];
  }
  if (act) {
    float* dst = Pout + (size_t)g * 81 + i * NL;
#pragma unroll
    for (int j = 0; j < NL; ++j) dst[j] = P[j];
  }
}

// ---------------- Kernel 3: per-batch combine (num + den fold) ----------------
__global__ __launch_bounds__(64) void combine_k(
    const float* __restrict__ e, const int* __restrict__ labels,
    const float* __restrict__ start_t, const float* __restrict__ end_t,
    const float* __restrict__ trans, const float* __restrict__ Pmat,
    float* __restrict__ llh, int B, int T, int C) {
  const int TOK = T - 2;
  const int b = blockIdx.x, lane = threadIdx.x;
  const float* eb = e + (size_t)b * TOK * NL;
  const int* lb = labels + (size_t)b * T + 1;

  // ---- numerator: chain-free, data-parallel over t ----
  const int g0r = lb[0];
  const int tg0 = (g0r == -100) ? 0 : g0r;
  float nsum = 0.f;
  int pack = -1;  // (t<<4)|tag of last masked step
  for (int t = 1 + lane; t < TOK; t += 64) {
    const int gr = lb[t], pr = lb[t - 1];
    if (gr != -100) {
      const int cur = gr;
      const int prev = (pr == -100) ? 0 : pr;
      nsum += trans[prev * NL + cur] + eb[t * NL + cur];
      pack = (t << 4) | cur;
    }
  }
#pragma unroll
  for (int off = 32; off; off >>= 1) {
    nsum += __shfl_xor(nsum, off);
    pack = max(pack, __shfl_xor(pack, off));
  }
  const int last = (pack < 0) ? tg0 : (pack & 15);
  const float num = start_t[tg0] + eb[tg0] + nsum + end_t[last];

  // ---- denominator: fold C chunk matrices ----
  float alpha = (lane < NL) ? (start_t[lane] + eb[lane]) : -1e30f;
  for (int c = 0; c < C; ++c) {
    const float* Pc = Pmat + ((size_t)b * C + c) * 81;
    float col[NL];
#pragma unroll
    for (int i = 0; i < NL; ++i)
      col[i] = (lane < NL) ? Pc[i * NL + lane] : -1e30f;
    float s[NL];
    float mx = -1e30f;
#pragma unroll
    for (int i = 0; i < NL; ++i) {
      const float ai = __shfl(alpha, i);
      s[i] = ai + col[i];
      mx = fmaxf(mx, s[i]);
    }
    float sum = 0.f;
#pragma unroll
    for (int i = 0; i < NL; ++i) sum += __expf(s[i] - mx);
    const float nx = mx + __logf(sum);
    alpha = (lane < NL) ? nx : -1e30f;
  }
  const float v = (lane < NL) ? (alpha + end_t[lane]) : -1e30f;
  float mx = v;
#pragma unroll
  for (int off = 32; off; off >>= 1) mx = fmaxf(mx, __shfl_xor(mx, off));
  float sum = (lane < NL) ? __expf(v - mx) : 0.f;
#pragma unroll
  for (int off = 32; off; off >>= 1) sum += __shfl_xor(sum, off);
  const float den = mx + __logf(sum);
  if (lane == 0) llh[b] = num - den;
}

// ---------------- Kernel 4: -mean(llh) ----------------
__global__ __launch_bounds__(64) void reduce_k(const float* __restrict__ llh,
                                               float* __restrict__ out, int B) {
  float v = 0.f;
  for (int i = threadIdx.x; i < B; i += 64) v += llh[i];
#pragma unroll
  for (int off = 32; off; off >>= 1) v += __shfl_xor(v, off);
  if (threadIdx.x == 0) out[0] = -v / (float)B;
}

extern "C" void kernel_launch(void* const* d_in, const int* in_sizes, int n_in,
                              void* d_out, int out_size, void* d_ws,
                              size_t ws_size, hipStream_t stream) {
  const float* hs     = (const float*)d_in[0];
  const float* w      = (const float*)d_in[1];
  const float* bias   = (const float*)d_in[2];
  const float* st     = (const float*)d_in[3];
  const float* et     = (const float*)d_in[4];
  const float* tr     = (const float*)d_in[5];
  const int*   amask  = (const int*)d_in[6];
  const int*   labels = (const int*)d_in[7];

  const int T = 512;
  const int B = in_sizes[6] / T;
  const int TOK = T - 2;
  const int C = (TOK - 1 + LCH - 1) / LCH;  // chunks of the 509 recurrence steps

  float* e    = (float*)d_ws;                 // (B, TOK, 9)
  float* llh  = e + (size_t)B * TOK * NL;     // (B,)
  float* Pmat = llh + B;                      // (B*C, 81)

  logits_k<<<768, 256, 0, stream>>>(hs, w, bias, amask, e, B, T);
  const int nG = B * C;
  chunk_k<<<(nG + 6) / 7, 64, 0, stream>>>(e, labels, tr, Pmat, B, T, C);
  combine_k<<<B, 64, 0, stream>>>(e, labels, st, et, tr, Pmat, llh, B, T, C);
  reduce_k<<<1, 64, 0, stream>>>(llh, (float*)d_out, B);
}

// Round 12
// 90.784 us; speedup vs baseline: 1.9149x; 1.9149x over previous
//
#include <hip/hip_runtime.h>
#include <math.h>

#define HIDDEN 1024
#define NL 9
#define LEAN_TAU 0.25f
#define LEAN_DELTA 0.35f
#define LCH 16
#define AST 1032  // LDS row stride in shorts (1024 + 8 pad)

typedef __attribute__((ext_vector_type(8))) short short8v;
typedef __attribute__((ext_vector_type(4))) float f32x4;

__device__ inline unsigned short f2b(float x) {  // fp32 -> bf16 (RNE)
  unsigned u = __float_as_uint(x);
  return (unsigned short)((u + 0x7fffu + ((u >> 16) & 1u)) >> 16);
}

// ---------------- mega kernel: one block per (batch, chunk) -----------------
// Stage 16 token rows + 9 weight rows to LDS (bf16), 32 MFMAs on wave0 compute
// slots 0..15 (R10's silicon-proven fragment layout), wave1 computes slot 16
// (last step of chunk) in fp32, top-2/lean applied in-block, then the chunk's
// 9x9 log-semiring product (wave0 lanes 0-8) and numerator partial (wave1)
// run from LDS. e never touches global memory.
__global__ __launch_bounds__(256) void mega_k(
    const float* __restrict__ hs, const float* __restrict__ w,
    const float* __restrict__ bias, const int* __restrict__ amask,
    const int* __restrict__ labels, const float* __restrict__ trans,
    float* __restrict__ Pout, float* __restrict__ nsumO,
    int* __restrict__ packO, float* __restrict__ e0row,
    int B, int T, int C) {
  const int TOK = T - 2;
  const int b = blockIdx.x / C, c = blockIdx.x - b * C;
  const int tid = threadIdx.x;
  const int wave = tid >> 6, lane = tid & 63;

  __shared__ unsigned short aT[16][AST];  // 16 token rows, bf16
  __shared__ unsigned short bT[NL][AST];  // 9 weight rows, bf16
  __shared__ float elog[17][NL];          // adjusted logits, slots 0..16
  __shared__ int mskS[LCH];

  // ---- stage A: slots 0..15 (token tt = c*16 + j), fp32->bf16, coalesced ----
  {
    const int j = tid >> 4, u = tid & 15;
    int tt = c * LCH + j;
    if (tt > TOK - 1) tt = TOK - 1;  // clamp; never used beyond len
    const float* row = hs + ((size_t)b * T + tt + 1) * HIDDEN;
#pragma unroll
    for (int q = 0; q < 16; ++q) {
      const float4 f = *reinterpret_cast<const float4*>(row + q * 64 + u * 4);
      uint2 pk;
      pk.x = (unsigned)f2b(f.x) | ((unsigned)f2b(f.y) << 16);
      pk.y = (unsigned)f2b(f.z) | ((unsigned)f2b(f.w) << 16);
      *reinterpret_cast<uint2*>(&aT[j][q * 64 + u * 4]) = pk;
    }
  }
  // ---- stage B: 9 weight rows ----
  if (tid < 144) {
    const int l = tid >> 4, u = tid & 15;
    const float* row = w + (size_t)l * HIDDEN;
#pragma unroll
    for (int q = 0; q < 16; ++q) {
      const float4 f = *reinterpret_cast<const float4*>(row + q * 64 + u * 4);
      uint2 pk;
      pk.x = (unsigned)f2b(f.x) | ((unsigned)f2b(f.y) << 16);
      pk.y = (unsigned)f2b(f.z) | ((unsigned)f2b(f.w) << 16);
      *reinterpret_cast<uint2*>(&bT[l][q * 64 + u * 4]) = pk;
    }
  } else if (tid < 160) {
    const int s = tid - 144;  // step mask: t = 1+c*16+s valid iff c*16+s <= TOK-2
    mskS[s] = (c * LCH + s <= TOK - 2)
                  ? (labels[(size_t)b * T + 2 + c * LCH + s] != -100 ? 1 : 0)
                  : 0;
  }
  __syncthreads();

  if (wave == 0) {
    // ---- MFMA: 16 tokens x 9 labels over K=1024 (32 x 16x16x32 bf16) ----
    const int g = lane >> 4, cc = lane & 15;
    const int brow = (cc < NL) ? cc : 0;
    const bool bz = (cc >= NL);
    f32x4 acc = {0.f, 0.f, 0.f, 0.f};
#pragma unroll
    for (int sl = 0; sl < 32; ++sl) {
      const short8v a =
          *reinterpret_cast<const short8v*>(&aT[cc][sl * 32 + g * 8]);
      short8v bb =
          *reinterpret_cast<const short8v*>(&bT[brow][sl * 32 + g * 8]);
      if (bz) {
#pragma unroll
        for (int z = 0; z < 8; ++z) bb[z] = 0;
      }
      acc = __builtin_amdgcn_mfma_f32_16x16x32_bf16(a, bb, acc, 0, 0, 0);
    }
    // epilogue (R10-proven C/D mapping: row=g*4+j, col=cc=label)
    const float bc = (cc < NL) ? bias[cc] : 0.f;
#pragma unroll
    for (int j = 0; j < 4; ++j) {
      const int slot = g * 4 + j;
      int tt = c * LCH + slot;
      if (tt > TOK - 1) tt = TOK - 1;
      const float v = acc[j] + bc;
      float m1 = (cc < NL) ? v : -1e30f, m2 = -1e30f;
#pragma unroll
      for (int off = 1; off < 16; off <<= 1) {
        const float om1 = __shfl_xor(m1, off);
        const float om2 = __shfl_xor(m2, off);
        const float hi = fmaxf(m1, om1);
        const float lo = fminf(m1, om1);
        m2 = fmaxf(lo, fmaxf(m2, om2));
        m1 = hi;
      }
      const bool unc = (m1 - m2 < LEAN_TAU) && (amask[b * T + tt + 1] != 0);
      const float vout = v + ((unc && cc == 0) ? LEAN_DELTA : 0.f);
      if (cc < NL) elog[slot][cc] = vout;
    }
  } else if (wave == 1) {
    // ---- slot 16 (= step 15 of this chunk) via fp32 dot, R8-proven code ----
    int tt = c * LCH + 16;
    if (tt > TOK - 1) tt = TOK - 1;
    const float4* row =
        reinterpret_cast<const float4*>(hs + ((size_t)b * T + tt + 1) * HIDDEN);
    const float4* w4 = reinterpret_cast<const float4*>(w);
    float accv[NL];
#pragma unroll
    for (int l = 0; l < NL; ++l) accv[l] = 0.f;
#pragma unroll
    for (int k = 0; k < 4; ++k) {
      const float4 hv = row[lane + 64 * k];
#pragma unroll
      for (int l = 0; l < NL; ++l) {
        const float4 wv = w4[l * (HIDDEN / 4) + lane + 64 * k];
        accv[l] = fmaf(hv.x, wv.x,
                  fmaf(hv.y, wv.y,
                  fmaf(hv.z, wv.z, fmaf(hv.w, wv.w, accv[l]))));
      }
    }
#pragma unroll
    for (int l = 0; l < NL; ++l) {
      float v = accv[l];
#pragma unroll
      for (int off = 32; off; off >>= 1) v += __shfl_xor(v, off);
      accv[l] = v + bias[l];
    }
    float m1 = -1e30f, m2 = -1e30f;
#pragma unroll
    for (int l = 0; l < NL; ++l) {
      const float v = accv[l];
      if (v > m1) { m2 = m1; m1 = v; }
      else if (v > m2) { m2 = v; }
    }
    const bool unc = (m1 - m2 < LEAN_TAU) && (amask[b * T + tt + 1] != 0);
    if (unc) accv[0] += LEAN_DELTA;
    if (lane < NL) {
      float outv = accv[0];
#pragma unroll
      for (int l = 1; l < NL; ++l)
        if (lane == l) outv = accv[l];
      elog[16][lane] = outv;
    }
  }
  __syncthreads();

  int len = TOK - 1 - c * LCH;
  if (len > LCH) len = LCH;

  if (wave == 0) {
    // ---- chunk 9x9 log-semiring product (factored lse), lanes 0..8 ----
    const int i = (lane < NL) ? lane : 0;
    float W[NL][NL];
#pragma unroll
    for (int k = 0; k < NL; ++k)
#pragma unroll
      for (int j = 0; j < NL; ++j) W[k][j] = __expf(trans[k * NL + j]);
    float P[NL];
    {
      const int m0 = mskS[0];
#pragma unroll
      for (int j = 0; j < NL; ++j)
        P[j] = m0 ? (trans[i * NL + j] + elog[1][j])
                  : ((i == j) ? 0.f : -1e30f);
    }
    for (int s = 1; s < len; ++s) {
      const int mt = mskS[s];
      float mx = P[0];
#pragma unroll
      for (int k = 1; k < NL; ++k) mx = fmaxf(mx, P[k]);
      float E[NL];
#pragma unroll
      for (int k = 0; k < NL; ++k) E[k] = __expf(P[k] - mx);
      float Pn[NL];
#pragma unroll
      for (int j = 0; j < NL; ++j) {
        float sum = 0.f;
#pragma unroll
        for (int k = 0; k < NL; ++k) sum = fmaf(E[k], W[k][j], sum);
        Pn[j] = mx + __logf(sum) + elog[s + 1][j];
      }
#pragma unroll
      for (int j = 0; j < NL; ++j) P[j] = mt ? Pn[j] : P[j];
    }
    if (lane < NL) {
      float* dst = Pout + (size_t)blockIdx.x * 81 + lane * NL;
#pragma unroll
      for (int j = 0; j < NL; ++j) dst[j] = P[j];
    }
  } else if (wave == 1) {
    // ---- numerator partial for this chunk's steps ----
    float nval = 0.f;
    int pk = -1;
    const int s = lane;  // one step per lane (len <= 16)
    if (s < len) {
      const int t = 1 + c * LCH + s;
      const int gr = labels[(size_t)b * T + 1 + t];
      if (gr != -100) {
        const int pr = labels[(size_t)b * T + t];  // gold[t-1]
        const int prev = (pr == -100) ? 0 : pr;
        nval = trans[prev * NL + gr] + elog[s + 1][gr];
        pk = (t << 4) | gr;
      }
    }
#pragma unroll
    for (int off = 1; off < 16; off <<= 1) {
      nval += __shfl_xor(nval, off);
      pk = max(pk, __shfl_xor(pk, off));
    }
    if (lane == 0) {
      nsumO[blockIdx.x] = nval;
      packO[blockIdx.x] = pk;
    }
  } else if (wave == 2) {
    if (c == 0 && lane < NL) e0row[b * NL + lane] = elog[0][lane];
  }
}

// ---------------- combine: per-batch fold of chunk results ----------------
__global__ __launch_bounds__(64) void combine_k(
    const int* __restrict__ labels, const float* __restrict__ start_t,
    const float* __restrict__ end_t, const float* __restrict__ Pmat,
    const float* __restrict__ nsumO, const int* __restrict__ packO,
    const float* __restrict__ e0row, float* __restrict__ llh,
    int B, int T, int C) {
  const int b = blockIdx.x, lane = threadIdx.x;
  const int g0r = labels[(size_t)b * T + 1];
  const int tg0 = (g0r == -100) ? 0 : g0r;

  // numerator: sum chunk partials + pick global last tag
  float nsum = (lane < C) ? nsumO[b * C + lane] : 0.f;
  int pk = (lane < C) ? packO[b * C + lane] : -1;
#pragma unroll
  for (int off = 32; off; off >>= 1) {
    nsum += __shfl_xor(nsum, off);
    pk = max(pk, __shfl_xor(pk, off));
  }
  const int last = (pk < 0) ? tg0 : (pk & 15);
  const float num = start_t[tg0] + e0row[b * NL + tg0] + nsum + end_t[last];

  // denominator: fold C chunk matrices
  float alpha = (lane < NL) ? (start_t[lane] + e0row[b * NL + lane]) : -1e30f;
  for (int cc = 0; cc < C; ++cc) {
    const float* Pc = Pmat + ((size_t)b * C + cc) * 81;
    float col[NL];
#pragma unroll
    for (int i = 0; i < NL; ++i)
      col[i] = (lane < NL) ? Pc[i * NL + lane] : -1e30f;
    float s[NL], mx = -1e30f;
#pragma unroll
    for (int i = 0; i < NL; ++i) {
      const float ai = __shfl(alpha, i);
      s[i] = ai + col[i];
      mx = fmaxf(mx, s[i]);
    }
    float sum = 0.f;
#pragma unroll
    for (int i = 0; i < NL; ++i) sum += __expf(s[i] - mx);
    const float nx = mx + __logf(sum);
    alpha = (lane < NL) ? nx : -1e30f;
  }
  const float v = (lane < NL) ? (alpha + end_t[lane]) : -1e30f;
  float mx = v;
#pragma unroll
  for (int off = 32; off; off >>= 1) mx = fmaxf(mx, __shfl_xor(mx, off));
  float sum = (lane < NL) ? __expf(v - mx) : 0.f;
#pragma unroll
  for (int off = 32; off; off >>= 1) sum += __shfl_xor(sum, off);
  const float den = mx + __logf(sum);
  if (lane == 0) llh[b] = num - den;
}

// ---------------- -mean(llh) ----------------
__global__ __launch_bounds__(64) void reduce_k(const float* __restrict__ llh,
                                               float* __restrict__ out, int B) {
  float v = 0.f;
  for (int i = threadIdx.x; i < B; i += 64) v += llh[i];
#pragma unroll
  for (int off = 32; off; off >>= 1) v += __shfl_xor(v, off);
  if (threadIdx.x == 0) out[0] = -v / (float)B;
}

extern "C" void kernel_launch(void* const* d_in, const int* in_sizes, int n_in,
                              void* d_out, int out_size, void* d_ws,
                              size_t ws_size, hipStream_t stream) {
  const float* hs     = (const float*)d_in[0];
  const float* w      = (const float*)d_in[1];
  const float* bias   = (const float*)d_in[2];
  const float* st     = (const float*)d_in[3];
  const float* et     = (const float*)d_in[4];
  const float* tr     = (const float*)d_in[5];
  const int*   amask  = (const int*)d_in[6];
  const int*   labels = (const int*)d_in[7];

  const int T = 512;
  const int B = in_sizes[6] / T;
  const int TOK = T - 2;
  const int C = (TOK - 1 + LCH - 1) / LCH;  // 32 chunks of the 509 steps
  const int nG = B * C;

  float* Pout  = (float*)d_ws;                   // (nG, 81)
  float* nsumO = Pout + (size_t)nG * 81;         // (nG,)
  int*   packO = (int*)(nsumO + nG);             // (nG,)
  float* e0r   = (float*)(packO + nG);           // (B, 9)
  float* llh   = e0r + (size_t)B * NL;           // (B,)

  mega_k<<<nG, 256, 0, stream>>>(hs, w, bias, amask, labels, tr, Pout, nsumO,
                                 packO, e0r, B, T, C);
  combine_k<<<B, 64, 0, stream>>>(labels, st, et, Pout, nsumO, packO, e0r, llh,
                                  B, T, C);
  reduce_k<<<1, 64, 0, stream>>>(llh, (float*)d_out, B);
}

// Round 13
// 80.464 us; speedup vs baseline: 2.1605x; 1.1283x over previous
//
#include <hip/hip_runtime.h>
#include <math.h>

#define HIDDEN 1024
#define NL 9
#define LEAN_TAU 0.25f
#define LEAN_DELTA 0.35f
#define LCH 16  // CRF scan chunk length

// ---------------- Kernel 1: emission logits + lean adjust ----------------
// R13: R9's weights-in-registers wave-per-token GEMV + explicit 2-deep
// software pipeline: token t+1's row loads (+amask) are issued BEFORE token
// t's compute, so ~600cyc memory latency hides under ~900cyc FMA/shfl.
// Duty-cycle model (validated on R6/R7/R9): non-pipelined duty = 600/1500
// = 40% -> 2.1 TB/s measured; pipelined -> ~100% -> BW-bound.
// Named double buffers (hv0/hv1), unroll x2 - no dynamic indexing (scratch!).
__global__ __launch_bounds__(256) void logits_k(
    const float* __restrict__ hs, const float* __restrict__ w,
    const float* __restrict__ bias, const int* __restrict__ amask,
    float* __restrict__ e, int B, int T) {
  const int TOK = T - 2, nTok = B * TOK;
  const int lane = threadIdx.x & 63;
  const int wid = blockIdx.x * 4 + (threadIdx.x >> 6);
  const int nW = gridDim.x * 4;

  // lane owns float4 slices lane+64k of each row (same for hs and w rows)
  float4 w4[NL][4];
#pragma unroll
  for (int l = 0; l < NL; ++l)
#pragma unroll
    for (int k = 0; k < 4; ++k)
      w4[l][k] =
          reinterpret_cast<const float4*>(w + (size_t)l * HIDDEN)[lane + 64 * k];
  float bb[NL];
#pragma unroll
  for (int l = 0; l < NL; ++l) bb[l] = bias[l];

  float4 hv0[4], hv1[4];
  int am0 = 0, am1 = 0;

#define LOADTOK(HV, AM, TOKV)                                            \
  {                                                                      \
    const int b_ = (TOKV) / TOK, t_ = (TOKV)-b_ * TOK;                   \
    const float4* row_ = reinterpret_cast<const float4*>(                \
        hs + ((size_t)b_ * T + t_ + 1) * HIDDEN);                        \
    _Pragma("unroll") for (int k_ = 0; k_ < 4; ++k_) HV[k_] =            \
        row_[lane + 64 * k_];                                            \
    AM = amask[b_ * T + t_ + 1];                                         \
  }

#define PROCESS(HV, AM, TOKV)                                            \
  {                                                                      \
    float acc[NL];                                                       \
    _Pragma("unroll") for (int l = 0; l < NL; ++l) {                     \
      float a = 0.f;                                                     \
      _Pragma("unroll") for (int k = 0; k < 4; ++k) a =                  \
          fmaf(HV[k].x, w4[l][k].x,                                      \
          fmaf(HV[k].y, w4[l][k].y,                                      \
          fmaf(HV[k].z, w4[l][k].z, fmaf(HV[k].w, w4[l][k].w, a))));     \
      _Pragma("unroll") for (int off = 32; off; off >>= 1) a +=          \
          __shfl_xor(a, off);                                            \
      acc[l] = a + bb[l];                                                \
    }                                                                    \
    float m1 = -INFINITY, m2 = -INFINITY;                                \
    _Pragma("unroll") for (int l = 0; l < NL; ++l) {                     \
      const float v_ = acc[l];                                           \
      if (v_ > m1) { m2 = m1; m1 = v_; }                                 \
      else if (v_ > m2) { m2 = v_; }                                     \
    }                                                                    \
    if ((m1 - m2 < LEAN_TAU) && (AM != 0)) acc[0] += LEAN_DELTA;         \
    if (lane < NL) {                                                     \
      float outv = acc[0];                                               \
      _Pragma("unroll") for (int l = 1; l < NL; ++l) if (lane == l)      \
          outv = acc[l];                                                 \
      e[(size_t)(TOKV)*NL + lane] = outv;                                \
    }                                                                    \
  }

  int tok = wid;
  if (tok < nTok) LOADTOK(hv0, am0, tok);
  while (tok < nTok) {
    const int tokB = tok + nW;
    if (tokB < nTok) LOADTOK(hv1, am1, tokB);  // prefetch under compute
    PROCESS(hv0, am0, tok);
    tok = tokB;
    if (tok >= nTok) break;
    const int tokA = tok + nW;
    if (tokA < nTok) LOADTOK(hv0, am0, tokA);  // prefetch under compute
    PROCESS(hv1, am1, tok);
    tok = tokA;
  }
#undef LOADTOK
#undef PROCESS
}

// ---------------- Kernel 2: per-chunk log-space matrix products ----------------
// 7 chunks per wave; lane = sub*9 + i holds row i of chunk sub's 9x9 product.
// Factored logsumexp: W = exp(trans) in registers -> 9 exp + 9 log + 81 fma/step.
__global__ __launch_bounds__(64) void chunk_k(
    const float* __restrict__ e, const int* __restrict__ labels,
    const float* __restrict__ trans, float* __restrict__ Pout,
    int B, int T, int C) {
  const int TOK = T - 2;
  __shared__ float e2[7][LCH][NL];
  __shared__ float tr2[NL * NL];
  __shared__ int msk[7][LCH];
  const int tid = threadIdx.x;
  const int nG = B * C;
  const int gbase = blockIdx.x * 7;

  for (int idx = tid; idx < NL * NL; idx += 64) tr2[idx] = trans[idx];
  for (int idx = tid; idx < 7 * LCH * NL; idx += 64) {
    const int sub = idx / (LCH * NL), rem = idx % (LCH * NL);
    const int step = rem / NL, j = rem % NL;
    const int g = gbase + sub;
    if (g < nG) {
      const int b = g / C, c = g % C;
      const int t = 1 + c * LCH + step;
      if (t < TOK) e2[sub][step][j] = e[((size_t)b * TOK + t) * NL + j];
    }
  }
  for (int idx = tid; idx < 7 * LCH; idx += 64) {
    const int sub = idx / LCH, step = idx % LCH;
    const int g = gbase + sub;
    if (g < nG) {
      const int b = g / C, c = g % C;
      const int t = 1 + c * LCH + step;
      msk[sub][step] = (t < TOK) ? (labels[(size_t)b * T + 1 + t] != -100) : 0;
    }
  }
  __syncthreads();

  const int sub = tid / NL, i = tid % NL;  // sub==7 only for tid 63 (inactive)
  const int g = gbase + sub;
  const bool act = (sub < 7) && (g < nG);
  int len = 1;
  if (act) { const int c = g % C; len = min(LCH, TOK - (1 + c * LCH)); }

  float W[NL][NL];
#pragma unroll
  for (int k = 0; k < NL; ++k)
#pragma unroll
    for (int j = 0; j < NL; ++j) W[k][j] = __expf(tr2[k * NL + j]);

  float P[NL];
  {
    const int m0 = act ? msk[sub][0] : 0;
#pragma unroll
    for (int j = 0; j < NL; ++j)
      P[j] = m0 ? (tr2[i * NL + j] + e2[sub][0][j])
                : ((i == j) ? 0.f : -1e30f);
  }
  for (int step = 1; step < len; ++step) {
    const int mt = msk[sub][step];
    float mx = P[0];
#pragma unroll
    for (int k = 1; k < NL; ++k) mx = fmaxf(mx, P[k]);
    float E[NL];
#pragma unroll
    for (int k = 0; k < NL; ++k) E[k] = __expf(P[k] - mx);
    float Pn[NL];
#pragma unroll
    for (int j = 0; j < NL; ++j) {
      float s = 0.f;
#pragma unroll
      for (int k = 0; k < NL; ++k) s = fmaf(E[k], W[k][j], s);
      Pn[j] = mx + __logf(s) + e2[sub][step][j];
    }
#pragma unroll
    for (int j = 0; j < NL; ++j) P[j] = mt ? Pn[j] : P[j];
  }
  if (act) {
    float* dst = Pout + (size_t)g * 81 + i * NL;
#pragma unroll
    for (int j = 0; j < NL; ++j) dst[j] = P[j];
  }
}

// ---------------- Kernel 3: per-batch combine (num + den fold) ----------------
__global__ __launch_bounds__(64) void combine_k(
    const float* __restrict__ e, const int* __restrict__ labels,
    const float* __restrict__ start_t, const float* __restrict__ end_t,
    const float* __restrict__ trans, const float* __restrict__ Pmat,
    float* __restrict__ llh, int B, int T, int C) {
  const int TOK = T - 2;
  const int b = blockIdx.x, lane = threadIdx.x;
  const float* eb = e + (size_t)b * TOK * NL;
  const int* lb = labels + (size_t)b * T + 1;

  // ---- numerator: chain-free, data-parallel over t ----
  const int g0r = lb[0];
  const int tg0 = (g0r == -100) ? 0 : g0r;
  float nsum = 0.f;
  int pack = -1;  // (t<<4)|tag of last masked step
  for (int t = 1 + lane; t < TOK; t += 64) {
    const int gr = lb[t], pr = lb[t - 1];
    if (gr != -100) {
      const int cur = gr;
      const int prev = (pr == -100) ? 0 : pr;
      nsum += trans[prev * NL + cur] + eb[t * NL + cur];
      pack = (t << 4) | cur;
    }
  }
#pragma unroll
  for (int off = 32; off; off >>= 1) {
    nsum += __shfl_xor(nsum, off);
    pack = max(pack, __shfl_xor(pack, off));
  }
  const int last = (pack < 0) ? tg0 : (pack & 15);
  const float num = start_t[tg0] + eb[tg0] + nsum + end_t[last];

  // ---- denominator: fold C chunk matrices ----
  float alpha = (lane < NL) ? (start_t[lane] + eb[lane]) : -1e30f;
  for (int c = 0; c < C; ++c) {
    const float* Pc = Pmat + ((size_t)b * C + c) * 81;
    float col[NL];
#pragma unroll
    for (int i = 0; i < NL; ++i)
      col[i] = (lane < NL) ? Pc[i * NL + lane] : -1e30f;
    float s[NL];
    float mx = -1e30f;
#pragma unroll
    for (int i = 0; i < NL; ++i) {
      const float ai = __shfl(alpha, i);
      s[i] = ai + col[i];
      mx = fmaxf(mx, s[i]);
    }
    float sum = 0.f;
#pragma unroll
    for (int i = 0; i < NL; ++i) sum += __expf(s[i] - mx);
    const float nx = mx + __logf(sum);
    alpha = (lane < NL) ? nx : -1e30f;
  }
  const float v = (lane < NL) ? (alpha + end_t[lane]) : -1e30f;
  float mx = v;
#pragma unroll
  for (int off = 32; off; off >>= 1) mx = fmaxf(mx, __shfl_xor(mx, off));
  float sum = (lane < NL) ? __expf(v - mx) : 0.f;
#pragma unroll
  for (int off = 32; off; off >>= 1) sum += __shfl_xor(sum, off);
  const float den = mx + __logf(sum);
  if (lane == 0) llh[b] = num - den;
}

// ---------------- Kernel 4: -mean(llh) ----------------
__global__ __launch_bounds__(64) void reduce_k(const float* __restrict__ llh,
                                               float* __restrict__ out, int B) {
  float v = 0.f;
  for (int i = threadIdx.x; i < B; i += 64) v += llh[i];
#pragma unroll
  for (int off = 32; off; off >>= 1) v += __shfl_xor(v, off);
  if (threadIdx.x == 0) out[0] = -v / (float)B;
}

extern "C" void kernel_launch(void* const* d_in, const int* in_sizes, int n_in,
                              void* d_out, int out_size, void* d_ws,
                              size_t ws_size, hipStream_t stream) {
  const float* hs     = (const float*)d_in[0];
  const float* w      = (const float*)d_in[1];
  const float* bias   = (const float*)d_in[2];
  const float* st     = (const float*)d_in[3];
  const float* et     = (const float*)d_in[4];
  const float* tr     = (const float*)d_in[5];
  const int*   amask  = (const int*)d_in[6];
  const int*   labels = (const int*)d_in[7];

  const int T = 512;
  const int B = in_sizes[6] / T;
  const int TOK = T - 2;
  const int C = (TOK - 1 + LCH - 1) / LCH;  // chunks of the 509 recurrence steps

  float* e    = (float*)d_ws;                 // (B, TOK, 9)
  float* llh  = e + (size_t)B * TOK * NL;     // (B,)
  float* Pmat = llh + B;                      // (B*C, 81)

  logits_k<<<512, 256, 0, stream>>>(hs, w, bias, amask, e, B, T);
  const int nG = B * C;
  chunk_k<<<(nG + 6) / 7, 64, 0, stream>>>(e, labels, tr, Pmat, B, T, C);
  combine_k<<<B, 64, 0, stream>>>(e, labels, st, et, tr, Pmat, llh, B, T, C);
  reduce_k<<<1, 64, 0, stream>>>(llh, (float*)d_out, B);
}